// Round 13
// baseline (120.644 us; speedup 1.0000x reference)
//
#include <hip/hip_runtime.h>
#include <math.h>

#define NROWS 8192
#define BHALF 4096
#define DDIM  128
#define NSPLIT 16
#define COLS_PER_BLOCK (NROWS / NSPLIT)   // 512
#define CHUNK 32                          // cols staged per LDS chunk
#define NCHUNK (COLS_PER_BLOCK / CHUNK)   // 16

typedef __bf16 bf16;
typedef __bf16 bf16x2 __attribute__((ext_vector_type(2)));
typedef __bf16 bf16x8 __attribute__((ext_vector_type(8)));
typedef float  f32x4  __attribute__((ext_vector_type(4)));

#define MFMA(acc, va, vb) \
    acc = __builtin_amdgcn_mfma_f32_16x16x32_bf16(va, vb, acc, 0, 0, 0)

// opaque redefinition: forbids rematerialization of the fragment from memory
#define PIN4(x) asm volatile("" : "+v"(((float*)&(x))[0]), "+v"(((float*)&(x))[1]), \
                                  "+v"(((float*)&(x))[2]), "+v"(((float*)&(x))[3]))

#define C2F 2.8853900817779268f   // 2*log2(e)
#define SCF 1.6986433053702937f   // sqrt(2*log2(e))

// ---------------------------------------------------------------------------
// Kernel 1: L2-normalize, scale by sqrt(2*log2(e)), split fp32 -> bf16 hi+lo.
// ---------------------------------------------------------------------------
__global__ __launch_bounds__(256) void nt_prep(const float* __restrict__ zis,
                                               const float* __restrict__ zjs,
                                               bf16* __restrict__ rhi,
                                               bf16* __restrict__ rlo) {
    int row  = blockIdx.x * 4 + (threadIdx.x >> 6);
    int lane = threadIdx.x & 63;
    const float* src = (row < BHALF) ? (zis + (size_t)row * DDIM)
                                     : (zjs + (size_t)(row - BHALF) * DDIM);
    float2 v = ((const float2*)src)[lane];
    float ss = v.x * v.x + v.y * v.y;
    #pragma unroll
    for (int off = 1; off < 64; off <<= 1) ss += __shfl_xor(ss, off);
    float invs = SCF / fmaxf(sqrtf(ss), 1e-12f);
    float y0 = v.x * invs, y1 = v.y * invs;
    bf16 h0 = (bf16)y0, h1 = (bf16)y1;
    bf16 l0 = (bf16)(y0 - (float)h0), l1 = (bf16)(y1 - (float)h1);
    bf16x2 hv, lv;
    hv[0] = h0; hv[1] = h1; lv[0] = l0; lv[1] = l1;
    *(bf16x2*)(rhi + (size_t)row * DDIM + 2 * lane) = hv;
    *(bf16x2*)(rlo + (size_t)row * DDIM + 2 * lane) = lv;
}

// ---------------------------------------------------------------------------
// Kernel 2: sim GEMM (split-bf16, 16x16x32 MFMA) + fused exp2 sum.
// ILP fix (R9 post-mortem): per jt-tile the 24 MFMAs run as SIX independent
// accumulator chains of length 4 (2 row-groups x {hi*hi, hi*lo, lo*hi}),
// summed before exp2 — instead of R9's one serial 24-chain (MfmaUtil 38%).
// 4 waves x 32 rows/wave; 4-bit XOR slot swizzle (R9: 0 bank conflicts).
// ---------------------------------------------------------------------------
__global__ __launch_bounds__(256) void nt_sim(const bf16* __restrict__ rhi,
                                              const bf16* __restrict__ rlo,
                                              float* __restrict__ partial,
                                              float* __restrict__ posA) {
    // LDS: 2 buffers x (hi 8KB + lo 8KB) = 32 KB
    __shared__ __align__(16) char smem[32768];

    const int tid  = threadIdx.x;
    const int lane = tid & 63;
    const int w    = tid >> 6;      // wave 0..3
    const int q    = lane >> 4;     // 0..3
    const int r15  = lane & 15;

    const int i0 = blockIdx.x * 128;              // block row base
    const int j0 = blockIdx.y * COLS_PER_BLOCK;   // block col base
    const bool capture = (blockIdx.y == (unsigned)((i0 ^ BHALF) >> 9));

    // ---- row fragments (B operand), 16 frags = 64 VGPRs, pinned ----
    bf16x8 rh[2][4], rl[2][4];
    #pragma unroll
    for (int g = 0; g < 2; ++g) {
        const int row = i0 + w * 32 + g * 16 + r15;
        #pragma unroll
        for (int kk = 0; kk < 4; ++kk) {
            rh[g][kk] = *(const bf16x8*)(rhi + (size_t)row * DDIM + kk * 32 + q * 8);
            rl[g][kk] = *(const bf16x8*)(rlo + (size_t)row * DDIM + kk * 32 + q * 8);
            PIN4(rh[g][kk]);
            PIN4(rl[g][kk]);
        }
    }

    float s[2] = {0.0f, 0.0f};

    for (int c = 0; c <= NCHUNK; ++c) {
        // ---- stage chunk c into buffer c&1 ----
        // LDS per region: col*256B + slot*16B; stored slot sl holds source
        // slot sl^(col&15) (linear dst, inverse-swizzled source: rule 21).
        if (c < NCHUNK) {
            char* dstb = smem + (c & 1) * 16384;
            const int colbase = j0 + c * CHUNK;
            #pragma unroll
            for (int p = 0; p < 2; ++p) {
                const int L   = p * 256 + tid;        // 0..511 16B-slots
                const int col = L >> 4, sl = L & 15;
                const size_t soff = (size_t)(colbase + col) * DDIM
                                  + ((sl ^ (col & 15)) << 3);
                __builtin_amdgcn_global_load_lds(
                    (const __attribute__((address_space(1))) void*)(rhi + soff),
                    (__attribute__((address_space(3))) void*)(dstb + L * 16),
                    16, 0, 0);
                __builtin_amdgcn_global_load_lds(
                    (const __attribute__((address_space(1))) void*)(rlo + soff),
                    (__attribute__((address_space(3))) void*)(dstb + 8192 + L * 16),
                    16, 0, 0);
            }
        }
        if (c == 0) { __syncthreads(); continue; }

        // ---- compute chunk c-1 from buffer (c-1)&1 ----
        const char* bh = smem + ((c - 1) & 1) * 16384;
        const char* bl = bh + 8192;
        const int cc = c - 1;
        #pragma unroll
        for (int jt = 0; jt < 2; ++jt) {
            const int cb = (jt * 16 + r15) * 256;   // col&15 == r15
            bf16x8 ch[4], cl[4];
            #pragma unroll
            for (int kk = 0; kk < 4; ++kk) {
                const int pok = ((((kk << 2) | q)) ^ r15) << 4;
                ch[kk] = *(const bf16x8*)(bh + cb + pok);
                cl[kk] = *(const bf16x8*)(bl + cb + pok);
            }
            // six independent accumulator chains of length 4
            f32x4 hh[2], hl[2], lh[2];
            #pragma unroll
            for (int g = 0; g < 2; ++g) {
                hh[g] = f32x4{-C2F, -C2F, -C2F, -C2F};
                hl[g] = f32x4{0.0f, 0.0f, 0.0f, 0.0f};
                lh[g] = f32x4{0.0f, 0.0f, 0.0f, 0.0f};
            }
            #pragma unroll
            for (int kk = 0; kk < 4; ++kk) {
                #pragma unroll
                for (int g = 0; g < 2; ++g) {
                    MFMA(hh[g], ch[kk], rh[g][kk]);
                    MFMA(hl[g], ch[kk], rl[g][kk]);
                    MFMA(lh[g], cl[kk], rh[g][kk]);
                }
            }
            const int jbase = j0 + cc * CHUNK + jt * 16;
            #pragma unroll
            for (int g = 0; g < 2; ++g) {
                f32x4 av = hh[g] + hl[g] + lh[g];   // C2*sim - C2
                s[g] += (exp2f(av[0]) + exp2f(av[1]))
                      + (exp2f(av[2]) + exp2f(av[3]));
                // positive-pair logit capture (wave-uniform skip in 15/16 blocks)
                if (capture) {
                    const int ig = i0 + w * 32 + g * 16 + r15;
                    const int rel = (ig ^ BHALF) - jbase;
                    float v01 = (rel & 1) ? av[1] : av[0];
                    float v23 = (rel & 1) ? av[3] : av[2];
                    float v   = (rel & 2) ? v23 : v01;
                    if (rel >= 0 && rel < 16 && (rel >> 2) == q) posA[ig] = v;
                }
            }
        }
        __syncthreads();
    }

    // ---- per-row totals: reduce over q groups (lanes sharing a row) ----
    #pragma unroll
    for (int g = 0; g < 2; ++g) {
        float st = s[g];
        st += __shfl_xor(st, 16);
        st += __shfl_xor(st, 32);
        if (q == g)
            partial[(size_t)blockIdx.y * NROWS + i0 + w * 32 + g * 16 + r15] = st;
    }
}

// ---------------------------------------------------------------------------
// Kernel 3: merge partials, lse = 2 + log(sum - 1), pos = 2*(a+C2)/C2,
// mean over rows. 8 blocks + one atomicAdd each (out pre-zeroed by memset).
// ---------------------------------------------------------------------------
__global__ __launch_bounds__(1024) void nt_final(const float* __restrict__ partial,
                                                 const float* __restrict__ posA,
                                                 float* __restrict__ out) {
    int i = blockIdx.x * 1024 + threadIdx.x;
    float ssum = 0.0f;
    #pragma unroll
    for (int p = 0; p < NSPLIT; ++p) ssum += partial[(size_t)p * NROWS + i];
    float a = posA[i];                        // C2*dot_pos - C2
    float acc = 2.0f + logf(ssum - 1.0f) - 2.0f * (a + C2F) / C2F;

    #pragma unroll
    for (int off = 1; off < 64; off <<= 1) acc += __shfl_xor(acc, off);
    __shared__ float wsum[16];
    int tid = threadIdx.x;
    if ((tid & 63) == 0) wsum[tid >> 6] = acc;
    __syncthreads();
    if (tid == 0) {
        float t = 0.0f;
        #pragma unroll
        for (int k = 0; k < 16; ++k) t += wsum[k];
        atomicAdd(out, t * (1.0f / (float)NROWS));
    }
}

// ---------------------------------------------------------------------------
extern "C" void kernel_launch(void* const* d_in, const int* in_sizes, int n_in,
                              void* d_out, int out_size, void* d_ws, size_t ws_size,
                              hipStream_t stream) {
    const float* zis = (const float*)d_in[0];
    const float* zjs = (const float*)d_in[1];
    float* out = (float*)d_out;

    char* ws = (char*)d_ws;
    bf16*  rhi     = (bf16*)ws;                                   // 2 MB
    bf16*  rlo     = (bf16*)(ws + (size_t)NROWS * DDIM * 2);      // 2 MB
    float* partial = (float*)(ws + (size_t)NROWS * DDIM * 4);     // 512 KB
    float* posA    = (float*)(ws + (size_t)NROWS * DDIM * 4
                                 + (size_t)NSPLIT * NROWS * 4);   // 32 KB

    hipMemsetAsync(out, 0, sizeof(float), stream);
    nt_prep <<<NROWS / 4, 256, 0, stream>>>(zis, zjs, rhi, rlo);
    nt_sim  <<<dim3(NROWS / 128, NSPLIT), 256, 0, stream>>>(rhi, rlo, partial, posA);
    nt_final<<<NROWS / 1024, 1024, 0, stream>>>(partial, posA, out);
}